// Round 25
// baseline (78.172 us; speedup 1.0000x reference)
//
#include <hip/hip_runtime.h>
#include <cstddef>
#include <cstdint>

// ---------------------------------------------------------------------------
// MILModel7 forward — R25: R21 structure (77.8 us, reproduced 4x) + T5
// s_setprio(1) around MFMA clusters. Mechanism: 2 blocks/CU drift through
// different phases -> cross-block wave role diversity -> scheduler can favor
// MFMA-issuing waves. Zero-risk hint (no sync change). Pre-committed read:
// null (77.3-78.3) -> R21 final; gain -> free improvement.
//
// Exact math: softmax over axis=1 of (s_i + s_j + Wb) -> j-terms cancel ->
// scores = softmax(s, axis=n). f_u = f_v (source bug kept).
// Validated constraint: time tracks barrier-pair count at ~2.1 us/pair.
// ---------------------------------------------------------------------------

typedef __attribute__((ext_vector_type(8))) short short8;
typedef __attribute__((ext_vector_type(4))) float float4v;

#define MFMA16(a, b, c) __builtin_amdgcn_mfma_f32_16x16x32_bf16((a), (b), (c), 0, 0, 0)
#define PRIO_HI() __builtin_amdgcn_s_setprio(1)
#define PRIO_LO() __builtin_amdgcn_s_setprio(0)

__device__ __forceinline__ unsigned short f2bf(float f) {
    union { float f; unsigned u; } v; v.f = f;
    unsigned r = (v.u + 0x7fffu + ((v.u >> 16) & 1u)) >> 16;
    return (unsigned short)r;
}
__device__ __forceinline__ float bf2f(unsigned short h) {
    union { unsigned u; float f; } v; v.u = ((unsigned)h) << 16;
    return v.f;
}
__device__ __forceinline__ float bf2f_s(short h) { return bf2f((unsigned short)h); }

// truncation split: x ~= hi + lo, |err| <= 2^-16 |x|
__device__ __forceinline__ void bfsplit(float x, short& h, short& l) {
    union { float f; unsigned u; } v; v.f = x;
    h = (short)(v.u >> 16);
    union { unsigned u; float f; } hv; hv.u = v.u & 0xffff0000u;
    union { float f; unsigned u; } lv; lv.f = x - hv.f;
    l = (short)(lv.u >> 16);
}

__device__ __forceinline__ float tanh_fast(float x) {
    float e = __builtin_exp2f(x * 2.885390081777927f);
    return 1.f - 2.f / (e + 1.f);
}
__device__ __forceinline__ float sigmoid_fast(float x) {
    return 1.f / (1.f + __builtin_exp2f(-x * 1.4426950408889634f));
}

// async global->LDS, 16 B per lane (wave-uniform base + lane*16 dest).
__device__ __forceinline__ void gload_lds16(const void* g, void* l) {
#if __has_builtin(__builtin_amdgcn_global_load_lds)
    __builtin_amdgcn_global_load_lds(
        (const __attribute__((address_space(1))) unsigned int*)g,
        (__attribute__((address_space(3))) unsigned int*)l, 16, 0, 0);
#else
    *(uint4*)l = *(const uint4*)g;
#endif
}

// ---------------------------------------------------------------------------
// prep: split weights into bf16 (hi/lo) MFMA B-fragment layout.
// Frag layout: elem index ((nf*KS + ks)*64 + lane)*8 + j  holds
//   W[n = (lane&15)+16*nf][k = ks*32 + (lane>>4)*8 + j]
// W1h is RNE bf16 -> usable standalone (2-term GEMM1).
// ---------------------------------------------------------------------------
__global__ __launch_bounds__(256)
void prep(const float* __restrict__ vfc_w, const float* __restrict__ afc_w,
          const float* __restrict__ am_v_w, const float* __restrict__ am_a_w,
          const float* __restrict__ V_w,
          unsigned short* __restrict__ W1h, unsigned short* __restrict__ W1l,
          unsigned short* __restrict__ W1bh, unsigned short* __restrict__ W1bl,
          unsigned short* __restrict__ W2v, unsigned short* __restrict__ W2a,
          unsigned short* __restrict__ W3)
{
    int t = blockIdx.x * 256 + threadIdx.x;
    if (t < 65536) {                       // vfc_w (128x512), hi (RNE) + lo
        int j = t & 7, lane = (t >> 3) & 63, ks = (t >> 9) & 15, nf = (t >> 13) & 7;
        int n = (lane & 15) + 16 * nf, k = ks * 32 + (lane >> 4) * 8 + j;
        float x = vfc_w[n * 512 + k];
        unsigned short h = f2bf(x);
        W1h[t] = h; W1l[t] = f2bf(x - bf2f(h));
    } else if (t < 81920) {                // afc_w (128x128), hi+lo
        int u = t - 65536;
        int j = u & 7, lane = (u >> 3) & 63, ks = (u >> 9) & 3, nf = (u >> 11) & 7;
        int n = (lane & 15) + 16 * nf, k = ks * 32 + (lane >> 4) * 8 + j;
        float x = afc_w[n * 128 + k];
        unsigned short h = f2bf(x);
        W1bh[u] = h; W1bl[u] = f2bf(x - bf2f(h));
    } else if (t < 98304) {                // am_v_w, single
        int u = t - 81920;
        int j = u & 7, lane = (u >> 3) & 63, ks = (u >> 9) & 3, nf = (u >> 11) & 7;
        int n = (lane & 15) + 16 * nf, k = ks * 32 + (lane >> 4) * 8 + j;
        W2v[u] = f2bf(am_v_w[n * 128 + k]);
    } else if (t < 114688) {               // am_a_w, single
        int u = t - 98304;
        int j = u & 7, lane = (u >> 3) & 63, ks = (u >> 9) & 3, nf = (u >> 11) & 7;
        int n = (lane & 15) + 16 * nf, k = ks * 32 + (lane >> 4) * 8 + j;
        W2a[u] = f2bf(am_a_w[n * 128 + k]);
    } else if (t < 122880) {               // V_w (64x128), single
        int u = t - 114688;
        int j = u & 7, lane = (u >> 3) & 63, ks = (u >> 9) & 3, nf = (u >> 11) & 3;
        int n = (lane & 15) + 16 * nf, k = ks * 32 + (lane >> 4) * 8 + j;
        W3[u] = f2bf(V_w[n * 128 + k]);
    }
}

// ---------------------------------------------------------------------------
// milA: fused per-wave chain. 4 waves/block, 16 rows/wave, grid 1024.
// GEMM1: 4 supersteps x 4 ks, hi-only (32 frags = 32 KB slice), 2-term MFMA.
// GEMM1b/GEMM2: 2 supersteps x 2 ks (32 KB hi/lo or v/a slices).
// LDS = 32K (bstage) + 16K (vo1s) + 16K (axs) = 64 KB -> 2 blocks/CU.
// ---------------------------------------------------------------------------
__global__ __launch_bounds__(256, 2)
void milA(const float* __restrict__ vfeat, const float* __restrict__ afeat,
          const float* __restrict__ vfc_b, const float* __restrict__ afc_b,
          const float* __restrict__ am_v_b, const float* __restrict__ am_a_b,
          const float* __restrict__ am_o_w, const float* __restrict__ am_o_b,
          const float* __restrict__ V_b, const float* __restrict__ W_w,
          const unsigned short* __restrict__ W1h,
          const unsigned short* __restrict__ W1bh, const unsigned short* __restrict__ W1bl,
          const unsigned short* __restrict__ W2v, const unsigned short* __restrict__ W2a,
          const unsigned short* __restrict__ W3,
          float* __restrict__ ffeat_out, float* __restrict__ s_out)
{
    __shared__ __align__(16) unsigned short bstage[16384];  // 32 KB
    __shared__ __align__(16) unsigned short vo1s[8192];     // 16 KB
    __shared__ __align__(16) unsigned short axs[8192];      // 16 KB

    const int tid = threadIdx.x;
    const int lane = tid & 63, wid = tid >> 6;
    const int lr = lane & 15, lg = lane >> 4;
    const int row0 = blockIdx.x * 64 + wid * 16;    // flat row base (b*2048+n)

    const float* ap  = vfeat + (size_t)(row0 + lr) * 512 + lg * 8;
    const float* apb = afeat + (size_t)(row0 + lr) * 128 + lg * 8;

    // ================= GEMM1: vo1 = relu(vfeat @ vfc^T + b), K=512 ============
    // 4 supersteps x 4 ks; stage 32 hi-frags (32 KB); 2-term (ah+al)*bh.
    float4v acc1[8];
#pragma unroll
    for (int nf = 0; nf < 8; ++nf)
#pragma unroll
        for (int i = 0; i < 4; ++i) acc1[nf][i] = 0.f;

    float4 acur[8], anxt[8];                // 4 ks x 2 float4 per batch
#pragma unroll
    for (int q = 0; q < 8; ++q)
        acur[q] = *(const float4*)(ap + (q >> 1) * 32 + (q & 1) * 4);

    for (int s = 0; s < 4; ++s) {
        __syncthreads();                    // bstage readers done
#pragma unroll
        for (int i = 0; i < 8; ++i) {       // stage 32 frags (4ks x 8nf, hi)
            const int f = wid * 8 + i;
            const int ksl = f >> 3, nf = f & 7;
            const unsigned short* src = W1h
                + (size_t)(nf * 16 + (s * 4 + ksl)) * 512 + (size_t)lane * 8;
            gload_lds16(src, &bstage[f * 512 + lane * 8]);
        }
        __syncthreads();                    // stage visible

        // batch-issue next superstep's A (ages one full compute phase)
        if (s < 3) {
            const float* apn = ap + (s + 1) * 128;
#pragma unroll
            for (int q = 0; q < 8; ++q)
                anxt[q] = *(const float4*)(apn + (q >> 1) * 32 + (q & 1) * 4);
        } else {                            // ALL of afeat's A (4 ks)
#pragma unroll
            for (int q = 0; q < 8; ++q)
                anxt[q] = *(const float4*)(apb + (q >> 1) * 32 + (q & 1) * 4);
        }

#pragma unroll
        for (int ksl = 0; ksl < 4; ++ksl) {
            short8 ah, al;
            {
                const float4 x0 = acur[ksl * 2], x1 = acur[ksl * 2 + 1];
                const float xs[8] = {x0.x, x0.y, x0.z, x0.w, x1.x, x1.y, x1.z, x1.w};
#pragma unroll
                for (int j = 0; j < 8; ++j) {
                    short h, l; bfsplit(xs[j], h, l);
                    ah[j] = h; al[j] = l;
                }
            }
            PRIO_HI();
#pragma unroll
            for (int nf = 0; nf < 8; ++nf) {
                const short8 bh = *(const short8*)&bstage[(ksl * 8 + nf) * 512 + lane * 8];
                acc1[nf] = MFMA16(ah, bh, acc1[nf]);
                acc1[nf] = MFMA16(al, bh, acc1[nf]);
            }
            PRIO_LO();
        }
#pragma unroll
        for (int q = 0; q < 8; ++q) acur[q] = anxt[q];
    }
    // epilogue: bias+relu (exact f32 kept in acc1), bf16 copy to swizzled LDS
#pragma unroll
    for (int nf = 0; nf < 8; ++nf) {
        const float bb = vfc_b[lr + 16 * nf];
#pragma unroll
        for (int r = 0; r < 4; ++r) {
            float v = fmaxf(acc1[nf][r] + bb, 0.f);
            acc1[nf][r] = v;
            const int row = lg * 4 + r;
            const int col = lr + 16 * nf;
            vo1s[wid * 2048 + row * 128 + (col ^ ((row & 7) << 3))] = f2bf(v);
        }
    }

    // ================= GEMM1b: ax = relu(afeat @ afc^T + b), K=128 ============
    // 2 supersteps x 2 ks, full hi/lo; A resident in acur (ks 0..3).
    float4v acc1b[8];
#pragma unroll
    for (int nf = 0; nf < 8; ++nf)
#pragma unroll
        for (int i = 0; i < 4; ++i) acc1b[nf][i] = 0.f;

    for (int s = 0; s < 2; ++s) {
        __syncthreads();
#pragma unroll
        for (int i = 0; i < 8; ++i) {       // 32 frags: 2ks x {8 hi, 8 lo}
            const int f = wid * 8 + i;
            const int ksl = f >> 4, rest = f & 15, isl = rest >> 3, nf = rest & 7;
            const unsigned short* src = (isl ? W1bl : W1bh)
                + (size_t)(nf * 4 + (s * 2 + ksl)) * 512 + (size_t)lane * 8;
            gload_lds16(src, &bstage[f * 512 + lane * 8]);
        }
        __syncthreads();

#pragma unroll
        for (int ksl = 0; ksl < 2; ++ksl) {
            const int ks = s * 2 + ksl;     // global afeat ks (0..3)
            short8 ah, al;
            {
                const float4 x0 = acur[ks * 2], x1 = acur[ks * 2 + 1];
                const float xs[8] = {x0.x, x0.y, x0.z, x0.w, x1.x, x1.y, x1.z, x1.w};
#pragma unroll
                for (int j = 0; j < 8; ++j) {
                    short h, l; bfsplit(xs[j], h, l);
                    ah[j] = h; al[j] = l;
                }
            }
            PRIO_HI();
#pragma unroll
            for (int nf = 0; nf < 8; ++nf) {
                const short8 bh = *(const short8*)&bstage[(ksl * 16 + nf) * 512 + lane * 8];
                const short8 bl = *(const short8*)&bstage[(ksl * 16 + 8 + nf) * 512 + lane * 8];
                acc1b[nf] = MFMA16(ah, bh, acc1b[nf]);
                acc1b[nf] = MFMA16(ah, bl, acc1b[nf]);
                acc1b[nf] = MFMA16(al, bh, acc1b[nf]);
            }
            PRIO_LO();
        }
    }
#pragma unroll
    for (int nf = 0; nf < 8; ++nf) {
        const float bb = afc_b[lr + 16 * nf];
#pragma unroll
        for (int r = 0; r < 4; ++r) {
            float v = fmaxf(acc1b[nf][r] + bb, 0.f);
            acc1b[nf][r] = v;
            const int row = lg * 4 + r;
            const int col = lr + 16 * nf;
            axs[wid * 2048 + row * 128 + (col ^ ((row & 7) << 3))] = f2bf(v);
        }
    }

    // ============ GEMM2: h = vo1 @ am_v^T + ax @ am_a^T (single bf16) =========
    // 2 supersteps x 2 ks; stage = 2ks x {8 W2v, 8 W2a}.
    float4v acc2[8];
#pragma unroll
    for (int nf = 0; nf < 8; ++nf)
#pragma unroll
        for (int i = 0; i < 4; ++i) acc2[nf][i] = 0.f;

    for (int s = 0; s < 2; ++s) {
        __syncthreads();
#pragma unroll
        for (int i = 0; i < 8; ++i) {
            const int f = wid * 8 + i;
            const int ksl = f >> 4, rest = f & 15, isa = rest >> 3, nf = rest & 7;
            const unsigned short* src = (isa ? W2a : W2v)
                + (size_t)(nf * 4 + (s * 2 + ksl)) * 512 + (size_t)lane * 8;
            gload_lds16(src, &bstage[f * 512 + lane * 8]);
        }
        __syncthreads();

#pragma unroll
        for (int ksl = 0; ksl < 2; ++ksl) {
            const int ks = s * 2 + ksl;
            const int rdoff = (ks * 32 + lg * 8) ^ ((lr & 7) << 3);
            const short8 a2v = *(const short8*)&vo1s[wid * 2048 + lr * 128 + rdoff];
            const short8 a2a = *(const short8*)&axs[wid * 2048 + lr * 128 + rdoff];
            PRIO_HI();
#pragma unroll
            for (int nf = 0; nf < 8; ++nf) {
                const short8 bv = *(const short8*)&bstage[(ksl * 16 + nf) * 512 + lane * 8];
                const short8 ba = *(const short8*)&bstage[(ksl * 16 + 8 + nf) * 512 + lane * 8];
                acc2[nf] = MFMA16(a2v, bv, acc2[nf]);
                acc2[nf] = MFMA16(a2a, ba, acc2[nf]);
            }
            PRIO_LO();
        }
    }

    __syncthreads();   // all waves done with bstage (GEMM2)
    // stage all of W3 (16 KB); drains at the barrier AFTER att+ffeat -> hidden.
#pragma unroll
    for (int i = 0; i < 4; ++i) {
        const int f = wid * 4 + i;          // f = nf*4+ks
        gload_lds16(W3 + (size_t)f * 512 + lane * 8, &bstage[f * 512 + lane * 8]);
    }

    // ---- att = sigmoid(tanh(h).am_o + ob), per row ---------------------------
    float attc[4];
    {
        float bias2[8], wo[8];
#pragma unroll
        for (int nf = 0; nf < 8; ++nf) {
            const int c = lr + 16 * nf;
            bias2[nf] = am_v_b[c] + am_a_b[c];
            wo[nf] = am_o_w[c];
        }
        const float ob = am_o_b[0];
#pragma unroll
        for (int r = 0; r < 4; ++r) {
            float p = 0.f;
#pragma unroll
            for (int nf = 0; nf < 8; ++nf)
                p += tanh_fast(acc2[nf][r] + bias2[nf]) * wo[nf];
            p += __shfl_xor(p, 1);
            p += __shfl_xor(p, 2);
            p += __shfl_xor(p, 4);
            p += __shfl_xor(p, 8);
            attc[r] = sigmoid_fast(p + ob);
        }
    }

    // ---- ffeat = att*ax + vo1 (exact f32 from live accs) -> global -----------
#pragma unroll
    for (int nf = 0; nf < 8; ++nf)
#pragma unroll
        for (int r = 0; r < 4; ++r)
            ffeat_out[(size_t)(row0 + lg * 4 + r) * 128 + lr + 16 * nf] =
                attc[r] * acc1b[nf][r] + acc1[nf][r];

    // att for row lr via shfl broadcast (row q owned by lanes lg=q>>2, r=q&3)
    float attv;
    {
        const int srcl = (lr >> 2) << 4;
        const float b0 = __shfl(attc[0], srcl);
        const float b1 = __shfl(attc[1], srcl);
        const float b2 = __shfl(attc[2], srcl);
        const float b3 = __shfl(attc[3], srcl);
        attv = (lr & 2) ? ((lr & 1) ? b3 : b2) : ((lr & 1) ? b1 : b0);
    }

    __syncthreads();   // W3 stage drained + visible

    // ================= GEMM3: f_v = relu(ffeat @ V^T + Vb), N=64 ==============
    float4v acc3[4];
#pragma unroll
    for (int nf = 0; nf < 4; ++nf)
#pragma unroll
        for (int i = 0; i < 4; ++i) acc3[nf][i] = 0.f;

#pragma unroll
    for (int ks = 0; ks < 4; ++ks) {
        const int rdoff = (ks * 32 + lg * 8) ^ ((lr & 7) << 3);
        const short8 x8 = *(const short8*)&axs[wid * 2048 + lr * 128 + rdoff];
        const short8 v8 = *(const short8*)&vo1s[wid * 2048 + lr * 128 + rdoff];
        short8 a3;
#pragma unroll
        for (int j = 0; j < 8; ++j) {
            float f = attv * bf2f_s(x8[j]) + bf2f_s(v8[j]);
            a3[j] = (short)f2bf(f);
        }
        PRIO_HI();
#pragma unroll
        for (int nf = 0; nf < 4; ++nf) {
            const short8 b = *(const short8*)&bstage[(nf * 4 + ks) * 512 + lane * 8];
            acc3[nf] = MFMA16(a3, b, acc3[nf]);
        }
        PRIO_LO();
    }

    // ---- s = relu(f_v + V_b) . W_w -> ws -------------------------------------
    {
        float vb3[4], ww3[4];
#pragma unroll
        for (int nf = 0; nf < 4; ++nf) {
            const int c = lr + 16 * nf;
            vb3[nf] = V_b[c];
            ww3[nf] = W_w[c];
        }
#pragma unroll
        for (int r = 0; r < 4; ++r) {
            float q = 0.f;
#pragma unroll
            for (int nf = 0; nf < 4; ++nf)
                q += fmaxf(acc3[nf][r] + vb3[nf], 0.f) * ww3[nf];
            q += __shfl_xor(q, 1);
            q += __shfl_xor(q, 2);
            q += __shfl_xor(q, 4);
            q += __shfl_xor(q, 8);
            if (lr == 0) s_out[row0 + lg * 4 + r] = q;
        }
    }
}

// ---------------------------------------------------------------------------
// Phase B (proven). milB12 fuses softmax + scores + zfeat partials.
// ---------------------------------------------------------------------------
__device__ __forceinline__ float wred_sum(float v) {
#pragma unroll
    for (int m = 32; m >= 1; m >>= 1) v += __shfl_xor(v, m);
    return v;
}
__device__ __forceinline__ float wred_max(float v) {
#pragma unroll
    for (int m = 32; m >= 1; m >>= 1) v = fmaxf(v, __shfl_xor(v, m));
    return v;
}

__global__ __launch_bounds__(256)
void milB12(const float* __restrict__ s_in, const float* __restrict__ ffeat,
            float* __restrict__ scores_out, float* __restrict__ parts)
{
    __shared__ float red[4];
    __shared__ float sh[256];
    __shared__ float zbuf[256];

    const int t = threadIdx.x, w = t >> 6;
    const int b = blockIdx.x >> 3, part = blockIdx.x & 7;
    const float* sb = s_in + (size_t)b * 2048;

    float v[8];
#pragma unroll
    for (int q = 0; q < 8; ++q) v[q] = sb[q * 256 + t];
    float m = v[0];
#pragma unroll
    for (int q = 1; q < 8; ++q) m = fmaxf(m, v[q]);
    m = wred_max(m);
    if ((t & 63) == 0) red[w] = m;
    __syncthreads();
    const float bm = fmaxf(fmaxf(red[0], red[1]), fmaxf(red[2], red[3]));

    float sum = 0.f;
#pragma unroll
    for (int q = 0; q < 8; ++q) sum += expf(v[q] - bm);
    sum = wred_sum(sum);
    __syncthreads();
    if ((t & 63) == 0) red[w] = sum;
    __syncthreads();
    const float inv = 1.f / (red[0] + red[1] + red[2] + red[3]);

    const float sv = sb[part * 256 + t];
    const float sc = expf(sv - bm) * inv;
    scores_out[(size_t)b * 2048 + part * 256 + t] = sc;
    sh[t] = sc;
    __syncthreads();

    const int col = t & 127, half = t >> 7;
    const float* fb = ffeat + ((size_t)(b * 2048 + part * 256 + half * 128)) * 128 + col;
    const float* sp = sh + half * 128;
    float z = 0.f;
#pragma unroll 8
    for (int nn = 0; nn < 128; ++nn) z += sp[nn] * fb[(size_t)nn * 128];
    zbuf[t] = z;
    __syncthreads();
    if (t < 128) parts[((size_t)(b * 8 + part)) * 128 + t] = zbuf[t] + zbuf[t + 128];
}

__global__ __launch_bounds__(128)
void milB3(const float* __restrict__ parts, const float* __restrict__ cls_w,
           const float* __restrict__ cls_b, float* __restrict__ logits)
{
    __shared__ float zfs[128];
    const int t = threadIdx.x, b = blockIdx.x;
    float zf = 0.f;
#pragma unroll
    for (int p = 0; p < 8; ++p) zf += parts[((size_t)(b * 8 + p)) * 128 + t];
    zfs[t] = zf;
    __syncthreads();
    const int o = t >> 6, c = t & 63;
    float q = zfs[c] * cls_w[o * 128 + c] + zfs[c + 64] * cls_w[o * 128 + c + 64];
    q = wred_sum(q);
    if (c == 0) logits[b * 2 + o] = q + cls_b[o];
}

extern "C" void kernel_launch(void* const* d_in, const int* in_sizes, int n_in,
                              void* d_out, int out_size, void* d_ws, size_t ws_size,
                              hipStream_t stream)
{
    (void)in_sizes; (void)n_in; (void)out_size; (void)ws_size;
    const float* vfeat  = (const float*)d_in[0];
    const float* afeat  = (const float*)d_in[1];
    const float* vfc_w  = (const float*)d_in[2];
    const float* vfc_b  = (const float*)d_in[3];
    const float* afc_w  = (const float*)d_in[4];
    const float* afc_b  = (const float*)d_in[5];
    const float* am_v_w = (const float*)d_in[6];
    const float* am_v_b = (const float*)d_in[7];
    const float* am_a_w = (const float*)d_in[8];
    const float* am_a_b = (const float*)d_in[9];
    const float* am_o_w = (const float*)d_in[10];
    const float* am_o_b = (const float*)d_in[11];
    const float* V_w    = (const float*)d_in[12];
    const float* V_b    = (const float*)d_in[13];
    const float* W_w    = (const float*)d_in[14];
    // d_in[15] = W_b: cancels exactly in the softmax over axis=1 -> unused.
    const float* cls_w  = (const float*)d_in[16];
    const float* cls_b  = (const float*)d_in[17];

    float* scores = (float*)d_out;                 // 32*2048
    float* logits = (float*)d_out + 32 * 2048;     // 32*2

    char* ws = (char*)d_ws;
    float* ffeat_ws = (float*)ws;                              // 33,554,432 B
    float* s_ws     = (float*)(ws + 33554432);                 //    262,144 B
    float* parts_ws = (float*)(ws + 33816576);                 //    131,072 B
    unsigned short* W1h  = (unsigned short*)(ws + 33947648);   // 65536
    unsigned short* W1l  = W1h + 65536;
    unsigned short* W1bh = W1l + 65536;                        // 16384
    unsigned short* W1bl = W1bh + 16384;
    unsigned short* W2v  = W1bl + 16384;
    unsigned short* W2a  = W2v + 16384;
    unsigned short* W3   = W2a + 16384;                        // 8192; end ~34.4 MB

    prep<<<480, 256, 0, stream>>>(vfc_w, afc_w, am_v_w, am_a_w, V_w,
                                  W1h, W1l, W1bh, W1bl, W2v, W2a, W3);
    milA<<<1024, 256, 0, stream>>>(vfeat, afeat, vfc_b, afc_b, am_v_b, am_a_b,
                                   am_o_w, am_o_b, V_b, W_w,
                                   W1h, W1bh, W1bl, W2v, W2a, W3,
                                   ffeat_ws, s_ws);
    milB12<<<256, 256, 0, stream>>>(s_ws, ffeat_ws, scores, parts_ws);
    milB3<<<32, 128, 0, stream>>>(parts_ws, cls_w, cls_b, logits);
}

// Round 26
// 77.870 us; speedup vs baseline: 1.0039x; 1.0039x over previous
//
#include <hip/hip_runtime.h>
#include <cstddef>
#include <cstdint>

// ---------------------------------------------------------------------------
// MILModel7 forward — FINAL (77.8 us, reproduced 4x: R21-R24; T5 setprio
// probed null in R25 per pre-commit -> reverted).
//
// Exact math: softmax over axis=1 of (s_i + s_j + Wb) -> j-terms cancel ->
// scores = softmax(s, axis=n); the n x n pairwise matrix never exists.
// f_u = f_v (source bug kept).
//
// milA (4 waves x 16 rows, grid 1024, 64 KB LDS, 2 blocks/CU):
//   GEMM1 (K=512): 4 supersteps x 4ks, B hi-only RNE bf16, 2-term
//     (ah+al)*bh split MFMA (absmax pinned at 2^-10 by downstream vo1/ax
//     bf16 quantization, measured invariant R18/R21).
//   GEMM1b (K=128): 2 supersteps x 2ks, full hi/lo. A preloaded at GEMM1 tail.
//   GEMM2: 2 supersteps x 2ks single-bf16. W3 staged at GEMM2 tail, drains
//     under att+ffeat. GEMM3 + s-reduction close the chain.
// milB12: fused softmax + scores + zfeat partials. milB3: logits.
//
// Validated constraint: time tracks barrier-pair count at ~2.1 us/pair
// (R18: +4 pairs -> +9 us; R21: -4 pairs -> -8 us). Axis exhausted at
// 9 pairs within the 32 KB slice / 2 blocks-per-CU envelope. T5 setprio:
// null at 2 blocks/CU (R25). Counted-vmcnt: flat (R9). Pipes <=21%:
// structural bound, not a hardware roofline.
// ---------------------------------------------------------------------------

typedef __attribute__((ext_vector_type(8))) short short8;
typedef __attribute__((ext_vector_type(4))) float float4v;

#define MFMA16(a, b, c) __builtin_amdgcn_mfma_f32_16x16x32_bf16((a), (b), (c), 0, 0, 0)

__device__ __forceinline__ unsigned short f2bf(float f) {
    union { float f; unsigned u; } v; v.f = f;
    unsigned r = (v.u + 0x7fffu + ((v.u >> 16) & 1u)) >> 16;
    return (unsigned short)r;
}
__device__ __forceinline__ float bf2f(unsigned short h) {
    union { unsigned u; float f; } v; v.u = ((unsigned)h) << 16;
    return v.f;
}
__device__ __forceinline__ float bf2f_s(short h) { return bf2f((unsigned short)h); }

// truncation split: x ~= hi + lo, |err| <= 2^-16 |x|
__device__ __forceinline__ void bfsplit(float x, short& h, short& l) {
    union { float f; unsigned u; } v; v.f = x;
    h = (short)(v.u >> 16);
    union { unsigned u; float f; } hv; hv.u = v.u & 0xffff0000u;
    union { float f; unsigned u; } lv; lv.f = x - hv.f;
    l = (short)(lv.u >> 16);
}

__device__ __forceinline__ float tanh_fast(float x) {
    float e = __builtin_exp2f(x * 2.885390081777927f);
    return 1.f - 2.f / (e + 1.f);
}
__device__ __forceinline__ float sigmoid_fast(float x) {
    return 1.f / (1.f + __builtin_exp2f(-x * 1.4426950408889634f));
}

// async global->LDS, 16 B per lane (wave-uniform base + lane*16 dest).
__device__ __forceinline__ void gload_lds16(const void* g, void* l) {
#if __has_builtin(__builtin_amdgcn_global_load_lds)
    __builtin_amdgcn_global_load_lds(
        (const __attribute__((address_space(1))) unsigned int*)g,
        (__attribute__((address_space(3))) unsigned int*)l, 16, 0, 0);
#else
    *(uint4*)l = *(const uint4*)g;
#endif
}

// ---------------------------------------------------------------------------
// prep: split weights into bf16 (hi/lo) MFMA B-fragment layout.
// Frag layout: elem index ((nf*KS + ks)*64 + lane)*8 + j  holds
//   W[n = (lane&15)+16*nf][k = ks*32 + (lane>>4)*8 + j]
// W1h is RNE bf16 -> usable standalone (2-term GEMM1).
// ---------------------------------------------------------------------------
__global__ __launch_bounds__(256)
void prep(const float* __restrict__ vfc_w, const float* __restrict__ afc_w,
          const float* __restrict__ am_v_w, const float* __restrict__ am_a_w,
          const float* __restrict__ V_w,
          unsigned short* __restrict__ W1h, unsigned short* __restrict__ W1l,
          unsigned short* __restrict__ W1bh, unsigned short* __restrict__ W1bl,
          unsigned short* __restrict__ W2v, unsigned short* __restrict__ W2a,
          unsigned short* __restrict__ W3)
{
    int t = blockIdx.x * 256 + threadIdx.x;
    if (t < 65536) {                       // vfc_w (128x512), hi (RNE) + lo
        int j = t & 7, lane = (t >> 3) & 63, ks = (t >> 9) & 15, nf = (t >> 13) & 7;
        int n = (lane & 15) + 16 * nf, k = ks * 32 + (lane >> 4) * 8 + j;
        float x = vfc_w[n * 512 + k];
        unsigned short h = f2bf(x);
        W1h[t] = h; W1l[t] = f2bf(x - bf2f(h));
    } else if (t < 81920) {                // afc_w (128x128), hi+lo
        int u = t - 65536;
        int j = u & 7, lane = (u >> 3) & 63, ks = (u >> 9) & 3, nf = (u >> 11) & 7;
        int n = (lane & 15) + 16 * nf, k = ks * 32 + (lane >> 4) * 8 + j;
        float x = afc_w[n * 128 + k];
        unsigned short h = f2bf(x);
        W1bh[u] = h; W1bl[u] = f2bf(x - bf2f(h));
    } else if (t < 98304) {                // am_v_w, single
        int u = t - 81920;
        int j = u & 7, lane = (u >> 3) & 63, ks = (u >> 9) & 3, nf = (u >> 11) & 7;
        int n = (lane & 15) + 16 * nf, k = ks * 32 + (lane >> 4) * 8 + j;
        W2v[u] = f2bf(am_v_w[n * 128 + k]);
    } else if (t < 114688) {               // am_a_w, single
        int u = t - 98304;
        int j = u & 7, lane = (u >> 3) & 63, ks = (u >> 9) & 3, nf = (u >> 11) & 7;
        int n = (lane & 15) + 16 * nf, k = ks * 32 + (lane >> 4) * 8 + j;
        W2a[u] = f2bf(am_a_w[n * 128 + k]);
    } else if (t < 122880) {               // V_w (64x128), single
        int u = t - 114688;
        int j = u & 7, lane = (u >> 3) & 63, ks = (u >> 9) & 3, nf = (u >> 11) & 3;
        int n = (lane & 15) + 16 * nf, k = ks * 32 + (lane >> 4) * 8 + j;
        W3[u] = f2bf(V_w[n * 128 + k]);
    }
}

// ---------------------------------------------------------------------------
// milA: fused per-wave chain. 4 waves/block, 16 rows/wave, grid 1024.
// GEMM1: 4 supersteps x 4 ks, hi-only (32 frags = 32 KB slice), 2-term MFMA.
// GEMM1b/GEMM2: 2 supersteps x 2 ks (32 KB hi/lo or v/a slices).
// LDS = 32K (bstage) + 16K (vo1s) + 16K (axs) = 64 KB -> 2 blocks/CU.
// Barriers: 8 (G1) + 4 (G1b) + 4 (G2) + 2 (W3) = 18.
// ---------------------------------------------------------------------------
__global__ __launch_bounds__(256, 2)
void milA(const float* __restrict__ vfeat, const float* __restrict__ afeat,
          const float* __restrict__ vfc_b, const float* __restrict__ afc_b,
          const float* __restrict__ am_v_b, const float* __restrict__ am_a_b,
          const float* __restrict__ am_o_w, const float* __restrict__ am_o_b,
          const float* __restrict__ V_b, const float* __restrict__ W_w,
          const unsigned short* __restrict__ W1h,
          const unsigned short* __restrict__ W1bh, const unsigned short* __restrict__ W1bl,
          const unsigned short* __restrict__ W2v, const unsigned short* __restrict__ W2a,
          const unsigned short* __restrict__ W3,
          float* __restrict__ ffeat_out, float* __restrict__ s_out)
{
    __shared__ __align__(16) unsigned short bstage[16384];  // 32 KB
    __shared__ __align__(16) unsigned short vo1s[8192];     // 16 KB
    __shared__ __align__(16) unsigned short axs[8192];      // 16 KB

    const int tid = threadIdx.x;
    const int lane = tid & 63, wid = tid >> 6;
    const int lr = lane & 15, lg = lane >> 4;
    const int row0 = blockIdx.x * 64 + wid * 16;    // flat row base (b*2048+n)

    const float* ap  = vfeat + (size_t)(row0 + lr) * 512 + lg * 8;
    const float* apb = afeat + (size_t)(row0 + lr) * 128 + lg * 8;

    // ================= GEMM1: vo1 = relu(vfeat @ vfc^T + b), K=512 ============
    // 4 supersteps x 4 ks; stage 32 hi-frags (32 KB); 2-term (ah+al)*bh.
    float4v acc1[8];
#pragma unroll
    for (int nf = 0; nf < 8; ++nf)
#pragma unroll
        for (int i = 0; i < 4; ++i) acc1[nf][i] = 0.f;

    float4 acur[8], anxt[8];                // 4 ks x 2 float4 per batch
#pragma unroll
    for (int q = 0; q < 8; ++q)
        acur[q] = *(const float4*)(ap + (q >> 1) * 32 + (q & 1) * 4);

    for (int s = 0; s < 4; ++s) {
        __syncthreads();                    // bstage readers done
#pragma unroll
        for (int i = 0; i < 8; ++i) {       // stage 32 frags (4ks x 8nf, hi)
            const int f = wid * 8 + i;
            const int ksl = f >> 3, nf = f & 7;
            const unsigned short* src = W1h
                + (size_t)(nf * 16 + (s * 4 + ksl)) * 512 + (size_t)lane * 8;
            gload_lds16(src, &bstage[f * 512 + lane * 8]);
        }
        __syncthreads();                    // stage visible

        // batch-issue next superstep's A (ages one full compute phase)
        if (s < 3) {
            const float* apn = ap + (s + 1) * 128;
#pragma unroll
            for (int q = 0; q < 8; ++q)
                anxt[q] = *(const float4*)(apn + (q >> 1) * 32 + (q & 1) * 4);
        } else {                            // ALL of afeat's A (4 ks)
#pragma unroll
            for (int q = 0; q < 8; ++q)
                anxt[q] = *(const float4*)(apb + (q >> 1) * 32 + (q & 1) * 4);
        }

#pragma unroll
        for (int ksl = 0; ksl < 4; ++ksl) {
            short8 ah, al;
            {
                const float4 x0 = acur[ksl * 2], x1 = acur[ksl * 2 + 1];
                const float xs[8] = {x0.x, x0.y, x0.z, x0.w, x1.x, x1.y, x1.z, x1.w};
#pragma unroll
                for (int j = 0; j < 8; ++j) {
                    short h, l; bfsplit(xs[j], h, l);
                    ah[j] = h; al[j] = l;
                }
            }
#pragma unroll
            for (int nf = 0; nf < 8; ++nf) {
                const short8 bh = *(const short8*)&bstage[(ksl * 8 + nf) * 512 + lane * 8];
                acc1[nf] = MFMA16(ah, bh, acc1[nf]);
                acc1[nf] = MFMA16(al, bh, acc1[nf]);
            }
        }
#pragma unroll
        for (int q = 0; q < 8; ++q) acur[q] = anxt[q];
    }
    // epilogue: bias+relu (exact f32 kept in acc1), bf16 copy to swizzled LDS
#pragma unroll
    for (int nf = 0; nf < 8; ++nf) {
        const float bb = vfc_b[lr + 16 * nf];
#pragma unroll
        for (int r = 0; r < 4; ++r) {
            float v = fmaxf(acc1[nf][r] + bb, 0.f);
            acc1[nf][r] = v;
            const int row = lg * 4 + r;
            const int col = lr + 16 * nf;
            vo1s[wid * 2048 + row * 128 + (col ^ ((row & 7) << 3))] = f2bf(v);
        }
    }

    // ================= GEMM1b: ax = relu(afeat @ afc^T + b), K=128 ============
    // 2 supersteps x 2 ks, full hi/lo; A resident in acur (ks 0..3).
    float4v acc1b[8];
#pragma unroll
    for (int nf = 0; nf < 8; ++nf)
#pragma unroll
        for (int i = 0; i < 4; ++i) acc1b[nf][i] = 0.f;

    for (int s = 0; s < 2; ++s) {
        __syncthreads();
#pragma unroll
        for (int i = 0; i < 8; ++i) {       // 32 frags: 2ks x {8 hi, 8 lo}
            const int f = wid * 8 + i;
            const int ksl = f >> 4, rest = f & 15, isl = rest >> 3, nf = rest & 7;
            const unsigned short* src = (isl ? W1bl : W1bh)
                + (size_t)(nf * 4 + (s * 2 + ksl)) * 512 + (size_t)lane * 8;
            gload_lds16(src, &bstage[f * 512 + lane * 8]);
        }
        __syncthreads();

#pragma unroll
        for (int ksl = 0; ksl < 2; ++ksl) {
            const int ks = s * 2 + ksl;     // global afeat ks (0..3)
            short8 ah, al;
            {
                const float4 x0 = acur[ks * 2], x1 = acur[ks * 2 + 1];
                const float xs[8] = {x0.x, x0.y, x0.z, x0.w, x1.x, x1.y, x1.z, x1.w};
#pragma unroll
                for (int j = 0; j < 8; ++j) {
                    short h, l; bfsplit(xs[j], h, l);
                    ah[j] = h; al[j] = l;
                }
            }
#pragma unroll
            for (int nf = 0; nf < 8; ++nf) {
                const short8 bh = *(const short8*)&bstage[(ksl * 16 + nf) * 512 + lane * 8];
                const short8 bl = *(const short8*)&bstage[(ksl * 16 + 8 + nf) * 512 + lane * 8];
                acc1b[nf] = MFMA16(ah, bh, acc1b[nf]);
                acc1b[nf] = MFMA16(ah, bl, acc1b[nf]);
                acc1b[nf] = MFMA16(al, bh, acc1b[nf]);
            }
        }
    }
#pragma unroll
    for (int nf = 0; nf < 8; ++nf) {
        const float bb = afc_b[lr + 16 * nf];
#pragma unroll
        for (int r = 0; r < 4; ++r) {
            float v = fmaxf(acc1b[nf][r] + bb, 0.f);
            acc1b[nf][r] = v;
            const int row = lg * 4 + r;
            const int col = lr + 16 * nf;
            axs[wid * 2048 + row * 128 + (col ^ ((row & 7) << 3))] = f2bf(v);
        }
    }

    // ============ GEMM2: h = vo1 @ am_v^T + ax @ am_a^T (single bf16) =========
    // 2 supersteps x 2 ks; stage = 2ks x {8 W2v, 8 W2a}.
    float4v acc2[8];
#pragma unroll
    for (int nf = 0; nf < 8; ++nf)
#pragma unroll
        for (int i = 0; i < 4; ++i) acc2[nf][i] = 0.f;

    for (int s = 0; s < 2; ++s) {
        __syncthreads();
#pragma unroll
        for (int i = 0; i < 8; ++i) {
            const int f = wid * 8 + i;
            const int ksl = f >> 4, rest = f & 15, isa = rest >> 3, nf = rest & 7;
            const unsigned short* src = (isa ? W2a : W2v)
                + (size_t)(nf * 4 + (s * 2 + ksl)) * 512 + (size_t)lane * 8;
            gload_lds16(src, &bstage[f * 512 + lane * 8]);
        }
        __syncthreads();

#pragma unroll
        for (int ksl = 0; ksl < 2; ++ksl) {
            const int ks = s * 2 + ksl;
            const int rdoff = (ks * 32 + lg * 8) ^ ((lr & 7) << 3);
            const short8 a2v = *(const short8*)&vo1s[wid * 2048 + lr * 128 + rdoff];
            const short8 a2a = *(const short8*)&axs[wid * 2048 + lr * 128 + rdoff];
#pragma unroll
            for (int nf = 0; nf < 8; ++nf) {
                const short8 bv = *(const short8*)&bstage[(ksl * 16 + nf) * 512 + lane * 8];
                const short8 ba = *(const short8*)&bstage[(ksl * 16 + 8 + nf) * 512 + lane * 8];
                acc2[nf] = MFMA16(a2v, bv, acc2[nf]);
                acc2[nf] = MFMA16(a2a, ba, acc2[nf]);
            }
        }
    }

    __syncthreads();   // all waves done with bstage (GEMM2)
    // stage all of W3 (16 KB); drains at the barrier AFTER att+ffeat -> hidden.
#pragma unroll
    for (int i = 0; i < 4; ++i) {
        const int f = wid * 4 + i;          // f = nf*4+ks
        gload_lds16(W3 + (size_t)f * 512 + lane * 8, &bstage[f * 512 + lane * 8]);
    }

    // ---- att = sigmoid(tanh(h).am_o + ob), per row ---------------------------
    float attc[4];
    {
        float bias2[8], wo[8];
#pragma unroll
        for (int nf = 0; nf < 8; ++nf) {
            const int c = lr + 16 * nf;
            bias2[nf] = am_v_b[c] + am_a_b[c];
            wo[nf] = am_o_w[c];
        }
        const float ob = am_o_b[0];
#pragma unroll
        for (int r = 0; r < 4; ++r) {
            float p = 0.f;
#pragma unroll
            for (int nf = 0; nf < 8; ++nf)
                p += tanh_fast(acc2[nf][r] + bias2[nf]) * wo[nf];
            p += __shfl_xor(p, 1);
            p += __shfl_xor(p, 2);
            p += __shfl_xor(p, 4);
            p += __shfl_xor(p, 8);
            attc[r] = sigmoid_fast(p + ob);
        }
    }

    // ---- ffeat = att*ax + vo1 (exact f32 from live accs) -> global -----------
#pragma unroll
    for (int nf = 0; nf < 8; ++nf)
#pragma unroll
        for (int r = 0; r < 4; ++r)
            ffeat_out[(size_t)(row0 + lg * 4 + r) * 128 + lr + 16 * nf] =
                attc[r] * acc1b[nf][r] + acc1[nf][r];

    // att for row lr via shfl broadcast (row q owned by lanes lg=q>>2, r=q&3)
    float attv;
    {
        const int srcl = (lr >> 2) << 4;
        const float b0 = __shfl(attc[0], srcl);
        const float b1 = __shfl(attc[1], srcl);
        const float b2 = __shfl(attc[2], srcl);
        const float b3 = __shfl(attc[3], srcl);
        attv = (lr & 2) ? ((lr & 1) ? b3 : b2) : ((lr & 1) ? b1 : b0);
    }

    __syncthreads();   // W3 stage drained + visible

    // ================= GEMM3: f_v = relu(ffeat @ V^T + Vb), N=64 ==============
    float4v acc3[4];
#pragma unroll
    for (int nf = 0; nf < 4; ++nf)
#pragma unroll
        for (int i = 0; i < 4; ++i) acc3[nf][i] = 0.f;

#pragma unroll
    for (int ks = 0; ks < 4; ++ks) {
        const int rdoff = (ks * 32 + lg * 8) ^ ((lr & 7) << 3);
        const short8 x8 = *(const short8*)&axs[wid * 2048 + lr * 128 + rdoff];
        const short8 v8 = *(const short8*)&vo1s[wid * 2048 + lr * 128 + rdoff];
        short8 a3;
#pragma unroll
        for (int j = 0; j < 8; ++j) {
            float f = attv * bf2f_s(x8[j]) + bf2f_s(v8[j]);
            a3[j] = (short)f2bf(f);
        }
#pragma unroll
        for (int nf = 0; nf < 4; ++nf) {
            const short8 b = *(const short8*)&bstage[(nf * 4 + ks) * 512 + lane * 8];
            acc3[nf] = MFMA16(a3, b, acc3[nf]);
        }
    }

    // ---- s = relu(f_v + V_b) . W_w -> ws -------------------------------------
    {
        float vb3[4], ww3[4];
#pragma unroll
        for (int nf = 0; nf < 4; ++nf) {
            const int c = lr + 16 * nf;
            vb3[nf] = V_b[c];
            ww3[nf] = W_w[c];
        }
#pragma unroll
        for (int r = 0; r < 4; ++r) {
            float q = 0.f;
#pragma unroll
            for (int nf = 0; nf < 4; ++nf)
                q += fmaxf(acc3[nf][r] + vb3[nf], 0.f) * ww3[nf];
            q += __shfl_xor(q, 1);
            q += __shfl_xor(q, 2);
            q += __shfl_xor(q, 4);
            q += __shfl_xor(q, 8);
            if (lr == 0) s_out[row0 + lg * 4 + r] = q;
        }
    }
}

// ---------------------------------------------------------------------------
// Phase B (proven). milB12 fuses softmax + scores + zfeat partials.
// ---------------------------------------------------------------------------
__device__ __forceinline__ float wred_sum(float v) {
#pragma unroll
    for (int m = 32; m >= 1; m >>= 1) v += __shfl_xor(v, m);
    return v;
}
__device__ __forceinline__ float wred_max(float v) {
#pragma unroll
    for (int m = 32; m >= 1; m >>= 1) v = fmaxf(v, __shfl_xor(v, m));
    return v;
}

__global__ __launch_bounds__(256)
void milB12(const float* __restrict__ s_in, const float* __restrict__ ffeat,
            float* __restrict__ scores_out, float* __restrict__ parts)
{
    __shared__ float red[4];
    __shared__ float sh[256];
    __shared__ float zbuf[256];

    const int t = threadIdx.x, w = t >> 6;
    const int b = blockIdx.x >> 3, part = blockIdx.x & 7;
    const float* sb = s_in + (size_t)b * 2048;

    float v[8];
#pragma unroll
    for (int q = 0; q < 8; ++q) v[q] = sb[q * 256 + t];
    float m = v[0];
#pragma unroll
    for (int q = 1; q < 8; ++q) m = fmaxf(m, v[q]);
    m = wred_max(m);
    if ((t & 63) == 0) red[w] = m;
    __syncthreads();
    const float bm = fmaxf(fmaxf(red[0], red[1]), fmaxf(red[2], red[3]));

    float sum = 0.f;
#pragma unroll
    for (int q = 0; q < 8; ++q) sum += expf(v[q] - bm);
    sum = wred_sum(sum);
    __syncthreads();
    if ((t & 63) == 0) red[w] = sum;
    __syncthreads();
    const float inv = 1.f / (red[0] + red[1] + red[2] + red[3]);

    const float sv = sb[part * 256 + t];
    const float sc = expf(sv - bm) * inv;
    scores_out[(size_t)b * 2048 + part * 256 + t] = sc;
    sh[t] = sc;
    __syncthreads();

    const int col = t & 127, half = t >> 7;
    const float* fb = ffeat + ((size_t)(b * 2048 + part * 256 + half * 128)) * 128 + col;
    const float* sp = sh + half * 128;
    float z = 0.f;
#pragma unroll 8
    for (int nn = 0; nn < 128; ++nn) z += sp[nn] * fb[(size_t)nn * 128];
    zbuf[t] = z;
    __syncthreads();
    if (t < 128) parts[((size_t)(b * 8 + part)) * 128 + t] = zbuf[t] + zbuf[t + 128];
}

__global__ __launch_bounds__(128)
void milB3(const float* __restrict__ parts, const float* __restrict__ cls_w,
           const float* __restrict__ cls_b, float* __restrict__ logits)
{
    __shared__ float zfs[128];
    const int t = threadIdx.x, b = blockIdx.x;
    float zf = 0.f;
#pragma unroll
    for (int p = 0; p < 8; ++p) zf += parts[((size_t)(b * 8 + p)) * 128 + t];
    zfs[t] = zf;
    __syncthreads();
    const int o = t >> 6, c = t & 63;
    float q = zfs[c] * cls_w[o * 128 + c] + zfs[c + 64] * cls_w[o * 128 + c + 64];
    q = wred_sum(q);
    if (c == 0) logits[b * 2 + o] = q + cls_b[o];
}

extern "C" void kernel_launch(void* const* d_in, const int* in_sizes, int n_in,
                              void* d_out, int out_size, void* d_ws, size_t ws_size,
                              hipStream_t stream)
{
    (void)in_sizes; (void)n_in; (void)out_size; (void)ws_size;
    const float* vfeat  = (const float*)d_in[0];
    const float* afeat  = (const float*)d_in[1];
    const float* vfc_w  = (const float*)d_in[2];
    const float* vfc_b  = (const float*)d_in[3];
    const float* afc_w  = (const float*)d_in[4];
    const float* afc_b  = (const float*)d_in[5];
    const float* am_v_w = (const float*)d_in[6];
    const float* am_v_b = (const float*)d_in[7];
    const float* am_a_w = (const float*)d_in[8];
    const float* am_a_b = (const float*)d_in[9];
    const float* am_o_w = (const float*)d_in[10];
    const float* am_o_b = (const float*)d_in[11];
    const float* V_w    = (const float*)d_in[12];
    const float* V_b    = (const float*)d_in[13];
    const float* W_w    = (const float*)d_in[14];
    // d_in[15] = W_b: cancels exactly in the softmax over axis=1 -> unused.
    const float* cls_w  = (const float*)d_in[16];
    const float* cls_b  = (const float*)d_in[17];

    float* scores = (float*)d_out;                 // 32*2048
    float* logits = (float*)d_out + 32 * 2048;     // 32*2

    char* ws = (char*)d_ws;
    float* ffeat_ws = (float*)ws;                              // 33,554,432 B
    float* s_ws     = (float*)(ws + 33554432);                 //    262,144 B
    float* parts_ws = (float*)(ws + 33816576);                 //    131,072 B
    unsigned short* W1h  = (unsigned short*)(ws + 33947648);   // 65536
    unsigned short* W1l  = W1h + 65536;
    unsigned short* W1bh = W1l + 65536;                        // 16384
    unsigned short* W1bl = W1bh + 16384;
    unsigned short* W2v  = W1bl + 16384;
    unsigned short* W2a  = W2v + 16384;
    unsigned short* W3   = W2a + 16384;                        // 8192; end ~34.4 MB

    prep<<<480, 256, 0, stream>>>(vfc_w, afc_w, am_v_w, am_a_w, V_w,
                                  W1h, W1l, W1bh, W1bl, W2v, W2a, W3);
    milA<<<1024, 256, 0, stream>>>(vfeat, afeat, vfc_b, afc_b, am_v_b, am_a_b,
                                   am_o_w, am_o_b, V_b, W_w,
                                   W1h, W1bh, W1bl, W2v, W2a, W3,
                                   ffeat_ws, s_ws);
    milB12<<<256, 256, 0, stream>>>(s_ws, ffeat_ws, scores, parts_ws);
    milB3<<<32, 128, 0, stream>>>(parts_ws, cls_w, cls_b, logits);
}

// Round 27
// 77.658 us; speedup vs baseline: 1.0066x; 1.0027x over previous
//
#include <hip/hip_runtime.h>
#include <cstddef>
#include <cstdint>

// ---------------------------------------------------------------------------
// MILModel7 forward — FINAL (77.8 us, reproduced 5x: R21-R24, R26).
//
// Exact math: softmax over axis=1 of (s_i + s_j + Wb) -> j-terms cancel ->
// scores = softmax(s, axis=n); the n x n pairwise matrix never exists.
// f_u = f_v (source bug kept).
//
// milA (4 waves x 16 rows, grid 1024, 64 KB LDS, 2 blocks/CU):
//   GEMM1 (K=512): 4 supersteps x 4ks, B hi-only RNE bf16, 2-term
//     (ah+al)*bh split MFMA (absmax pinned at 2^-10 by downstream vo1/ax
//     bf16 quantization, measured invariant R18/R21).
//   GEMM1b (K=128): 2 supersteps x 2ks, full hi/lo. A preloaded at GEMM1 tail.
//   GEMM2: 2 supersteps x 2ks single-bf16. W3 staged at GEMM2 tail, drains
//     under att+ffeat. GEMM3 + s-reduction close the chain.
// milB12: fused softmax + scores + zfeat partials. milB3: logits.
//
// Validated constraint: time tracks barrier-pair count at ~2.1 us/pair
// (R18: +4 pairs -> +9 us; R21: -4 pairs -> -8 us). Axis exhausted at
// 9 pairs within the 32 KB slice / 2 blocks-per-CU envelope. T5 setprio:
// null (R25). Counted-vmcnt: flat (R9). Pipes <=21%: structural bound.
// ---------------------------------------------------------------------------

typedef __attribute__((ext_vector_type(8))) short short8;
typedef __attribute__((ext_vector_type(4))) float float4v;

#define MFMA16(a, b, c) __builtin_amdgcn_mfma_f32_16x16x32_bf16((a), (b), (c), 0, 0, 0)

__device__ __forceinline__ unsigned short f2bf(float f) {
    union { float f; unsigned u; } v; v.f = f;
    unsigned r = (v.u + 0x7fffu + ((v.u >> 16) & 1u)) >> 16;
    return (unsigned short)r;
}
__device__ __forceinline__ float bf2f(unsigned short h) {
    union { unsigned u; float f; } v; v.u = ((unsigned)h) << 16;
    return v.f;
}
__device__ __forceinline__ float bf2f_s(short h) { return bf2f((unsigned short)h); }

// truncation split: x ~= hi + lo, |err| <= 2^-16 |x|
__device__ __forceinline__ void bfsplit(float x, short& h, short& l) {
    union { float f; unsigned u; } v; v.f = x;
    h = (short)(v.u >> 16);
    union { unsigned u; float f; } hv; hv.u = v.u & 0xffff0000u;
    union { float f; unsigned u; } lv; lv.f = x - hv.f;
    l = (short)(lv.u >> 16);
}

__device__ __forceinline__ float tanh_fast(float x) {
    float e = __builtin_exp2f(x * 2.885390081777927f);
    return 1.f - 2.f / (e + 1.f);
}
__device__ __forceinline__ float sigmoid_fast(float x) {
    return 1.f / (1.f + __builtin_exp2f(-x * 1.4426950408889634f));
}

// async global->LDS, 16 B per lane (wave-uniform base + lane*16 dest).
__device__ __forceinline__ void gload_lds16(const void* g, void* l) {
#if __has_builtin(__builtin_amdgcn_global_load_lds)
    __builtin_amdgcn_global_load_lds(
        (const __attribute__((address_space(1))) unsigned int*)g,
        (__attribute__((address_space(3))) unsigned int*)l, 16, 0, 0);
#else
    *(uint4*)l = *(const uint4*)g;
#endif
}

// ---------------------------------------------------------------------------
// prep: split weights into bf16 (hi/lo) MFMA B-fragment layout.
// Frag layout: elem index ((nf*KS + ks)*64 + lane)*8 + j  holds
//   W[n = (lane&15)+16*nf][k = ks*32 + (lane>>4)*8 + j]
// W1h is RNE bf16 -> usable standalone (2-term GEMM1).
// ---------------------------------------------------------------------------
__global__ __launch_bounds__(256)
void prep(const float* __restrict__ vfc_w, const float* __restrict__ afc_w,
          const float* __restrict__ am_v_w, const float* __restrict__ am_a_w,
          const float* __restrict__ V_w,
          unsigned short* __restrict__ W1h, unsigned short* __restrict__ W1l,
          unsigned short* __restrict__ W1bh, unsigned short* __restrict__ W1bl,
          unsigned short* __restrict__ W2v, unsigned short* __restrict__ W2a,
          unsigned short* __restrict__ W3)
{
    int t = blockIdx.x * 256 + threadIdx.x;
    if (t < 65536) {                       // vfc_w (128x512), hi (RNE) + lo
        int j = t & 7, lane = (t >> 3) & 63, ks = (t >> 9) & 15, nf = (t >> 13) & 7;
        int n = (lane & 15) + 16 * nf, k = ks * 32 + (lane >> 4) * 8 + j;
        float x = vfc_w[n * 512 + k];
        unsigned short h = f2bf(x);
        W1h[t] = h; W1l[t] = f2bf(x - bf2f(h));
    } else if (t < 81920) {                // afc_w (128x128), hi+lo
        int u = t - 65536;
        int j = u & 7, lane = (u >> 3) & 63, ks = (u >> 9) & 3, nf = (u >> 11) & 7;
        int n = (lane & 15) + 16 * nf, k = ks * 32 + (lane >> 4) * 8 + j;
        float x = afc_w[n * 128 + k];
        unsigned short h = f2bf(x);
        W1bh[u] = h; W1bl[u] = f2bf(x - bf2f(h));
    } else if (t < 98304) {                // am_v_w, single
        int u = t - 81920;
        int j = u & 7, lane = (u >> 3) & 63, ks = (u >> 9) & 3, nf = (u >> 11) & 7;
        int n = (lane & 15) + 16 * nf, k = ks * 32 + (lane >> 4) * 8 + j;
        W2v[u] = f2bf(am_v_w[n * 128 + k]);
    } else if (t < 114688) {               // am_a_w, single
        int u = t - 98304;
        int j = u & 7, lane = (u >> 3) & 63, ks = (u >> 9) & 3, nf = (u >> 11) & 7;
        int n = (lane & 15) + 16 * nf, k = ks * 32 + (lane >> 4) * 8 + j;
        W2a[u] = f2bf(am_a_w[n * 128 + k]);
    } else if (t < 122880) {               // V_w (64x128), single
        int u = t - 114688;
        int j = u & 7, lane = (u >> 3) & 63, ks = (u >> 9) & 3, nf = (u >> 11) & 3;
        int n = (lane & 15) + 16 * nf, k = ks * 32 + (lane >> 4) * 8 + j;
        W3[u] = f2bf(V_w[n * 128 + k]);
    }
}

// ---------------------------------------------------------------------------
// milA: fused per-wave chain. 4 waves/block, 16 rows/wave, grid 1024.
// GEMM1: 4 supersteps x 4 ks, hi-only (32 frags = 32 KB slice), 2-term MFMA.
// GEMM1b/GEMM2: 2 supersteps x 2 ks (32 KB hi/lo or v/a slices).
// LDS = 32K (bstage) + 16K (vo1s) + 16K (axs) = 64 KB -> 2 blocks/CU.
// Barriers: 8 (G1) + 4 (G1b) + 4 (G2) + 2 (W3) = 18.
// ---------------------------------------------------------------------------
__global__ __launch_bounds__(256, 2)
void milA(const float* __restrict__ vfeat, const float* __restrict__ afeat,
          const float* __restrict__ vfc_b, const float* __restrict__ afc_b,
          const float* __restrict__ am_v_b, const float* __restrict__ am_a_b,
          const float* __restrict__ am_o_w, const float* __restrict__ am_o_b,
          const float* __restrict__ V_b, const float* __restrict__ W_w,
          const unsigned short* __restrict__ W1h,
          const unsigned short* __restrict__ W1bh, const unsigned short* __restrict__ W1bl,
          const unsigned short* __restrict__ W2v, const unsigned short* __restrict__ W2a,
          const unsigned short* __restrict__ W3,
          float* __restrict__ ffeat_out, float* __restrict__ s_out)
{
    __shared__ __align__(16) unsigned short bstage[16384];  // 32 KB
    __shared__ __align__(16) unsigned short vo1s[8192];     // 16 KB
    __shared__ __align__(16) unsigned short axs[8192];      // 16 KB

    const int tid = threadIdx.x;
    const int lane = tid & 63, wid = tid >> 6;
    const int lr = lane & 15, lg = lane >> 4;
    const int row0 = blockIdx.x * 64 + wid * 16;    // flat row base (b*2048+n)

    const float* ap  = vfeat + (size_t)(row0 + lr) * 512 + lg * 8;
    const float* apb = afeat + (size_t)(row0 + lr) * 128 + lg * 8;

    // ================= GEMM1: vo1 = relu(vfeat @ vfc^T + b), K=512 ============
    // 4 supersteps x 4 ks; stage 32 hi-frags (32 KB); 2-term (ah+al)*bh.
    float4v acc1[8];
#pragma unroll
    for (int nf = 0; nf < 8; ++nf)
#pragma unroll
        for (int i = 0; i < 4; ++i) acc1[nf][i] = 0.f;

    float4 acur[8], anxt[8];                // 4 ks x 2 float4 per batch
#pragma unroll
    for (int q = 0; q < 8; ++q)
        acur[q] = *(const float4*)(ap + (q >> 1) * 32 + (q & 1) * 4);

    for (int s = 0; s < 4; ++s) {
        __syncthreads();                    // bstage readers done
#pragma unroll
        for (int i = 0; i < 8; ++i) {       // stage 32 frags (4ks x 8nf, hi)
            const int f = wid * 8 + i;
            const int ksl = f >> 3, nf = f & 7;
            const unsigned short* src = W1h
                + (size_t)(nf * 16 + (s * 4 + ksl)) * 512 + (size_t)lane * 8;
            gload_lds16(src, &bstage[f * 512 + lane * 8]);
        }
        __syncthreads();                    // stage visible

        // batch-issue next superstep's A (ages one full compute phase)
        if (s < 3) {
            const float* apn = ap + (s + 1) * 128;
#pragma unroll
            for (int q = 0; q < 8; ++q)
                anxt[q] = *(const float4*)(apn + (q >> 1) * 32 + (q & 1) * 4);
        } else {                            // ALL of afeat's A (4 ks)
#pragma unroll
            for (int q = 0; q < 8; ++q)
                anxt[q] = *(const float4*)(apb + (q >> 1) * 32 + (q & 1) * 4);
        }

#pragma unroll
        for (int ksl = 0; ksl < 4; ++ksl) {
            short8 ah, al;
            {
                const float4 x0 = acur[ksl * 2], x1 = acur[ksl * 2 + 1];
                const float xs[8] = {x0.x, x0.y, x0.z, x0.w, x1.x, x1.y, x1.z, x1.w};
#pragma unroll
                for (int j = 0; j < 8; ++j) {
                    short h, l; bfsplit(xs[j], h, l);
                    ah[j] = h; al[j] = l;
                }
            }
#pragma unroll
            for (int nf = 0; nf < 8; ++nf) {
                const short8 bh = *(const short8*)&bstage[(ksl * 8 + nf) * 512 + lane * 8];
                acc1[nf] = MFMA16(ah, bh, acc1[nf]);
                acc1[nf] = MFMA16(al, bh, acc1[nf]);
            }
        }
#pragma unroll
        for (int q = 0; q < 8; ++q) acur[q] = anxt[q];
    }
    // epilogue: bias+relu (exact f32 kept in acc1), bf16 copy to swizzled LDS
#pragma unroll
    for (int nf = 0; nf < 8; ++nf) {
        const float bb = vfc_b[lr + 16 * nf];
#pragma unroll
        for (int r = 0; r < 4; ++r) {
            float v = fmaxf(acc1[nf][r] + bb, 0.f);
            acc1[nf][r] = v;
            const int row = lg * 4 + r;
            const int col = lr + 16 * nf;
            vo1s[wid * 2048 + row * 128 + (col ^ ((row & 7) << 3))] = f2bf(v);
        }
    }

    // ================= GEMM1b: ax = relu(afeat @ afc^T + b), K=128 ============
    // 2 supersteps x 2 ks, full hi/lo; A resident in acur (ks 0..3).
    float4v acc1b[8];
#pragma unroll
    for (int nf = 0; nf < 8; ++nf)
#pragma unroll
        for (int i = 0; i < 4; ++i) acc1b[nf][i] = 0.f;

    for (int s = 0; s < 2; ++s) {
        __syncthreads();
#pragma unroll
        for (int i = 0; i < 8; ++i) {       // 32 frags: 2ks x {8 hi, 8 lo}
            const int f = wid * 8 + i;
            const int ksl = f >> 4, rest = f & 15, isl = rest >> 3, nf = rest & 7;
            const unsigned short* src = (isl ? W1bl : W1bh)
                + (size_t)(nf * 4 + (s * 2 + ksl)) * 512 + (size_t)lane * 8;
            gload_lds16(src, &bstage[f * 512 + lane * 8]);
        }
        __syncthreads();

#pragma unroll
        for (int ksl = 0; ksl < 2; ++ksl) {
            const int ks = s * 2 + ksl;     // global afeat ks (0..3)
            short8 ah, al;
            {
                const float4 x0 = acur[ks * 2], x1 = acur[ks * 2 + 1];
                const float xs[8] = {x0.x, x0.y, x0.z, x0.w, x1.x, x1.y, x1.z, x1.w};
#pragma unroll
                for (int j = 0; j < 8; ++j) {
                    short h, l; bfsplit(xs[j], h, l);
                    ah[j] = h; al[j] = l;
                }
            }
#pragma unroll
            for (int nf = 0; nf < 8; ++nf) {
                const short8 bh = *(const short8*)&bstage[(ksl * 16 + nf) * 512 + lane * 8];
                const short8 bl = *(const short8*)&bstage[(ksl * 16 + 8 + nf) * 512 + lane * 8];
                acc1b[nf] = MFMA16(ah, bh, acc1b[nf]);
                acc1b[nf] = MFMA16(ah, bl, acc1b[nf]);
                acc1b[nf] = MFMA16(al, bh, acc1b[nf]);
            }
        }
    }
#pragma unroll
    for (int nf = 0; nf < 8; ++nf) {
        const float bb = afc_b[lr + 16 * nf];
#pragma unroll
        for (int r = 0; r < 4; ++r) {
            float v = fmaxf(acc1b[nf][r] + bb, 0.f);
            acc1b[nf][r] = v;
            const int row = lg * 4 + r;
            const int col = lr + 16 * nf;
            axs[wid * 2048 + row * 128 + (col ^ ((row & 7) << 3))] = f2bf(v);
        }
    }

    // ============ GEMM2: h = vo1 @ am_v^T + ax @ am_a^T (single bf16) =========
    // 2 supersteps x 2 ks; stage = 2ks x {8 W2v, 8 W2a}.
    float4v acc2[8];
#pragma unroll
    for (int nf = 0; nf < 8; ++nf)
#pragma unroll
        for (int i = 0; i < 4; ++i) acc2[nf][i] = 0.f;

    for (int s = 0; s < 2; ++s) {
        __syncthreads();
#pragma unroll
        for (int i = 0; i < 8; ++i) {
            const int f = wid * 8 + i;
            const int ksl = f >> 4, rest = f & 15, isa = rest >> 3, nf = rest & 7;
            const unsigned short* src = (isa ? W2a : W2v)
                + (size_t)(nf * 4 + (s * 2 + ksl)) * 512 + (size_t)lane * 8;
            gload_lds16(src, &bstage[f * 512 + lane * 8]);
        }
        __syncthreads();

#pragma unroll
        for (int ksl = 0; ksl < 2; ++ksl) {
            const int ks = s * 2 + ksl;
            const int rdoff = (ks * 32 + lg * 8) ^ ((lr & 7) << 3);
            const short8 a2v = *(const short8*)&vo1s[wid * 2048 + lr * 128 + rdoff];
            const short8 a2a = *(const short8*)&axs[wid * 2048 + lr * 128 + rdoff];
#pragma unroll
            for (int nf = 0; nf < 8; ++nf) {
                const short8 bv = *(const short8*)&bstage[(ksl * 16 + nf) * 512 + lane * 8];
                const short8 ba = *(const short8*)&bstage[(ksl * 16 + 8 + nf) * 512 + lane * 8];
                acc2[nf] = MFMA16(a2v, bv, acc2[nf]);
                acc2[nf] = MFMA16(a2a, ba, acc2[nf]);
            }
        }
    }

    __syncthreads();   // all waves done with bstage (GEMM2)
    // stage all of W3 (16 KB); drains at the barrier AFTER att+ffeat -> hidden.
#pragma unroll
    for (int i = 0; i < 4; ++i) {
        const int f = wid * 4 + i;          // f = nf*4+ks
        gload_lds16(W3 + (size_t)f * 512 + lane * 8, &bstage[f * 512 + lane * 8]);
    }

    // ---- att = sigmoid(tanh(h).am_o + ob), per row ---------------------------
    float attc[4];
    {
        float bias2[8], wo[8];
#pragma unroll
        for (int nf = 0; nf < 8; ++nf) {
            const int c = lr + 16 * nf;
            bias2[nf] = am_v_b[c] + am_a_b[c];
            wo[nf] = am_o_w[c];
        }
        const float ob = am_o_b[0];
#pragma unroll
        for (int r = 0; r < 4; ++r) {
            float p = 0.f;
#pragma unroll
            for (int nf = 0; nf < 8; ++nf)
                p += tanh_fast(acc2[nf][r] + bias2[nf]) * wo[nf];
            p += __shfl_xor(p, 1);
            p += __shfl_xor(p, 2);
            p += __shfl_xor(p, 4);
            p += __shfl_xor(p, 8);
            attc[r] = sigmoid_fast(p + ob);
        }
    }

    // ---- ffeat = att*ax + vo1 (exact f32 from live accs) -> global -----------
#pragma unroll
    for (int nf = 0; nf < 8; ++nf)
#pragma unroll
        for (int r = 0; r < 4; ++r)
            ffeat_out[(size_t)(row0 + lg * 4 + r) * 128 + lr + 16 * nf] =
                attc[r] * acc1b[nf][r] + acc1[nf][r];

    // att for row lr via shfl broadcast (row q owned by lanes lg=q>>2, r=q&3)
    float attv;
    {
        const int srcl = (lr >> 2) << 4;
        const float b0 = __shfl(attc[0], srcl);
        const float b1 = __shfl(attc[1], srcl);
        const float b2 = __shfl(attc[2], srcl);
        const float b3 = __shfl(attc[3], srcl);
        attv = (lr & 2) ? ((lr & 1) ? b3 : b2) : ((lr & 1) ? b1 : b0);
    }

    __syncthreads();   // W3 stage drained + visible

    // ================= GEMM3: f_v = relu(ffeat @ V^T + Vb), N=64 ==============
    float4v acc3[4];
#pragma unroll
    for (int nf = 0; nf < 4; ++nf)
#pragma unroll
        for (int i = 0; i < 4; ++i) acc3[nf][i] = 0.f;

#pragma unroll
    for (int ks = 0; ks < 4; ++ks) {
        const int rdoff = (ks * 32 + lg * 8) ^ ((lr & 7) << 3);
        const short8 x8 = *(const short8*)&axs[wid * 2048 + lr * 128 + rdoff];
        const short8 v8 = *(const short8*)&vo1s[wid * 2048 + lr * 128 + rdoff];
        short8 a3;
#pragma unroll
        for (int j = 0; j < 8; ++j) {
            float f = attv * bf2f_s(x8[j]) + bf2f_s(v8[j]);
            a3[j] = (short)f2bf(f);
        }
#pragma unroll
        for (int nf = 0; nf < 4; ++nf) {
            const short8 b = *(const short8*)&bstage[(nf * 4 + ks) * 512 + lane * 8];
            acc3[nf] = MFMA16(a3, b, acc3[nf]);
        }
    }

    // ---- s = relu(f_v + V_b) . W_w -> ws -------------------------------------
    {
        float vb3[4], ww3[4];
#pragma unroll
        for (int nf = 0; nf < 4; ++nf) {
            const int c = lr + 16 * nf;
            vb3[nf] = V_b[c];
            ww3[nf] = W_w[c];
        }
#pragma unroll
        for (int r = 0; r < 4; ++r) {
            float q = 0.f;
#pragma unroll
            for (int nf = 0; nf < 4; ++nf)
                q += fmaxf(acc3[nf][r] + vb3[nf], 0.f) * ww3[nf];
            q += __shfl_xor(q, 1);
            q += __shfl_xor(q, 2);
            q += __shfl_xor(q, 4);
            q += __shfl_xor(q, 8);
            if (lr == 0) s_out[row0 + lg * 4 + r] = q;
        }
    }
}

// ---------------------------------------------------------------------------
// Phase B (proven). milB12 fuses softmax + scores + zfeat partials.
// ---------------------------------------------------------------------------
__device__ __forceinline__ float wred_sum(float v) {
#pragma unroll
    for (int m = 32; m >= 1; m >>= 1) v += __shfl_xor(v, m);
    return v;
}
__device__ __forceinline__ float wred_max(float v) {
#pragma unroll
    for (int m = 32; m >= 1; m >>= 1) v = fmaxf(v, __shfl_xor(v, m));
    return v;
}

__global__ __launch_bounds__(256)
void milB12(const float* __restrict__ s_in, const float* __restrict__ ffeat,
            float* __restrict__ scores_out, float* __restrict__ parts)
{
    __shared__ float red[4];
    __shared__ float sh[256];
    __shared__ float zbuf[256];

    const int t = threadIdx.x, w = t >> 6;
    const int b = blockIdx.x >> 3, part = blockIdx.x & 7;
    const float* sb = s_in + (size_t)b * 2048;

    float v[8];
#pragma unroll
    for (int q = 0; q < 8; ++q) v[q] = sb[q * 256 + t];
    float m = v[0];
#pragma unroll
    for (int q = 1; q < 8; ++q) m = fmaxf(m, v[q]);
    m = wred_max(m);
    if ((t & 63) == 0) red[w] = m;
    __syncthreads();
    const float bm = fmaxf(fmaxf(red[0], red[1]), fmaxf(red[2], red[3]));

    float sum = 0.f;
#pragma unroll
    for (int q = 0; q < 8; ++q) sum += expf(v[q] - bm);
    sum = wred_sum(sum);
    __syncthreads();
    if ((t & 63) == 0) red[w] = sum;
    __syncthreads();
    const float inv = 1.f / (red[0] + red[1] + red[2] + red[3]);

    const float sv = sb[part * 256 + t];
    const float sc = expf(sv - bm) * inv;
    scores_out[(size_t)b * 2048 + part * 256 + t] = sc;
    sh[t] = sc;
    __syncthreads();

    const int col = t & 127, half = t >> 7;
    const float* fb = ffeat + ((size_t)(b * 2048 + part * 256 + half * 128)) * 128 + col;
    const float* sp = sh + half * 128;
    float z = 0.f;
#pragma unroll 8
    for (int nn = 0; nn < 128; ++nn) z += sp[nn] * fb[(size_t)nn * 128];
    zbuf[t] = z;
    __syncthreads();
    if (t < 128) parts[((size_t)(b * 8 + part)) * 128 + t] = zbuf[t] + zbuf[t + 128];
}

__global__ __launch_bounds__(128)
void milB3(const float* __restrict__ parts, const float* __restrict__ cls_w,
           const float* __restrict__ cls_b, float* __restrict__ logits)
{
    __shared__ float zfs[128];
    const int t = threadIdx.x, b = blockIdx.x;
    float zf = 0.f;
#pragma unroll
    for (int p = 0; p < 8; ++p) zf += parts[((size_t)(b * 8 + p)) * 128 + t];
    zfs[t] = zf;
    __syncthreads();
    const int o = t >> 6, c = t & 63;
    float q = zfs[c] * cls_w[o * 128 + c] + zfs[c + 64] * cls_w[o * 128 + c + 64];
    q = wred_sum(q);
    if (c == 0) logits[b * 2 + o] = q + cls_b[o];
}

extern "C" void kernel_launch(void* const* d_in, const int* in_sizes, int n_in,
                              void* d_out, int out_size, void* d_ws, size_t ws_size,
                              hipStream_t stream)
{
    (void)in_sizes; (void)n_in; (void)out_size; (void)ws_size;
    const float* vfeat  = (const float*)d_in[0];
    const float* afeat  = (const float*)d_in[1];
    const float* vfc_w  = (const float*)d_in[2];
    const float* vfc_b  = (const float*)d_in[3];
    const float* afc_w  = (const float*)d_in[4];
    const float* afc_b  = (const float*)d_in[5];
    const float* am_v_w = (const float*)d_in[6];
    const float* am_v_b = (const float*)d_in[7];
    const float* am_a_w = (const float*)d_in[8];
    const float* am_a_b = (const float*)d_in[9];
    const float* am_o_w = (const float*)d_in[10];
    const float* am_o_b = (const float*)d_in[11];
    const float* V_w    = (const float*)d_in[12];
    const float* V_b    = (const float*)d_in[13];
    const float* W_w    = (const float*)d_in[14];
    // d_in[15] = W_b: cancels exactly in the softmax over axis=1 -> unused.
    const float* cls_w  = (const float*)d_in[16];
    const float* cls_b  = (const float*)d_in[17];

    float* scores = (float*)d_out;                 // 32*2048
    float* logits = (float*)d_out + 32 * 2048;     // 32*2

    char* ws = (char*)d_ws;
    float* ffeat_ws = (float*)ws;                              // 33,554,432 B
    float* s_ws     = (float*)(ws + 33554432);                 //    262,144 B
    float* parts_ws = (float*)(ws + 33816576);                 //    131,072 B
    unsigned short* W1h  = (unsigned short*)(ws + 33947648);   // 65536
    unsigned short* W1l  = W1h + 65536;
    unsigned short* W1bh = W1l + 65536;                        // 16384
    unsigned short* W1bl = W1bh + 16384;
    unsigned short* W2v  = W1bl + 16384;
    unsigned short* W2a  = W2v + 16384;
    unsigned short* W3   = W2a + 16384;                        // 8192; end ~34.4 MB

    prep<<<480, 256, 0, stream>>>(vfc_w, afc_w, am_v_w, am_a_w, V_w,
                                  W1h, W1l, W1bh, W1bl, W2v, W2a, W3);
    milA<<<1024, 256, 0, stream>>>(vfeat, afeat, vfc_b, afc_b, am_v_b, am_a_b,
                                   am_o_w, am_o_b, V_b, W_w,
                                   W1h, W1bh, W1bl, W2v, W2a, W3,
                                   ffeat_ws, s_ws);
    milB12<<<256, 256, 0, stream>>>(s_ws, ffeat_ws, scores, parts_ws);
    milB3<<<32, 128, 0, stream>>>(parts_ws, cls_w, cls_b, logits);
}